// Round 6
// baseline (440.447 us; speedup 1.0000x reference)
//
#include <hip/hip_runtime.h>
#include <hip/hip_bf16.h>

#define NTOK 8192
#define HDIM 4096
#define NEXP 64
#define CAP  160   // int(8192 * 1.25 / 64)
#define TB   16    // tokens per block in gemm
#define KC   128   // K chunk

// 2 MB device-global scratch for fp32 logits (no d_ws assumptions).
__device__ float g_logits[NTOK * NEXP];

// ---------------- Kernel 0: zero the fp32 mask region ----------------
__global__ __launch_bounds__(256) void init_out(float4* __restrict__ mask4, int n4) {
    int i = blockIdx.x * blockDim.x + threadIdx.x;
    if (i < n4) mask4[i] = float4{0.f, 0.f, 0.f, 0.f};
}

// ---------------- Kernel 1: logits = x @ gate_w (fp64 accumulate, LDS-staged) ----
// grid 512, block 256 (4 waves). Each wave: 64 lanes = 64 experts, 4 tokens.
__global__ __launch_bounds__(256) void gemm_logits(const float* __restrict__ x,
                                                   const float* __restrict__ w) {
    __shared__ float xs[TB][KC];      // 8 KB
    __shared__ float wsh[KC][NEXP];   // 32 KB
    const int tid  = threadIdx.x;
    const int lane = tid & 63;
    const int wv   = tid >> 6;
    const int t0   = blockIdx.x * TB;

    double acc[4] = {0.0, 0.0, 0.0, 0.0};

    const float4* x4 = (const float4*)x;
    const float4* w4 = (const float4*)w;
    float4* xs4 = (float4*)&xs[0][0];
    float4* ws4 = (float4*)&wsh[0][0];

    for (int kc = 0; kc < HDIM; kc += KC) {
        __syncthreads();
        #pragma unroll
        for (int j = 0; j < 8; ++j) {
            int i = tid + j * 256;
            ws4[i] = w4[(kc * NEXP) / 4 + i];
        }
        #pragma unroll
        for (int j = 0; j < 2; ++j) {
            int i = tid + j * 256;
            int t = i >> 5, c = i & 31;
            xs4[t * 32 + c] = x4[(size_t)(t0 + t) * (HDIM / 4) + (kc / 4) + c];
        }
        __syncthreads();

        #pragma unroll 4
        for (int k = 0; k < KC; ++k) {
            double wd = (double)wsh[k][lane];
            #pragma unroll
            for (int t = 0; t < 4; ++t)
                acc[t] = fma((double)xs[wv * 4 + t][k], wd, acc[t]);
        }
    }

    #pragma unroll
    for (int t = 0; t < 4; ++t)
        g_logits[(size_t)(t0 + wv * 4 + t) * NEXP + lane] = (float)acc[t];
}

// ---------------- Kernel 2: per-expert top-CAP selection (fp32 outputs) ---------
__global__ __launch_bounds__(256) void topk_kernel(float* __restrict__ out_idx,
                                                   float* __restrict__ out_mask) {
    const int e    = blockIdx.x;
    const int tid  = threadIdx.x;
    const int lane = tid & 63;
    const int wv   = tid >> 6;

    float v[32];
    #pragma unroll
    for (int j = 0; j < 32; ++j)
        v[j] = g_logits[(size_t)(tid + (j << 8)) * NEXP + e];

    unsigned int sel = 0u;   // bitmask of already-selected local slots

    __shared__ float sval[4];
    __shared__ int   sidx[4];
    __shared__ int   wtok;

    for (int c = 0; c < CAP; ++c) {
        // local argmax over unselected slots (ascending j => smallest token on tie)
        float bv = -3.4e38f;
        int   bj = 0;
        #pragma unroll
        for (int j = 0; j < 32; ++j) {
            bool ok = !((sel >> j) & 1u) && (v[j] > bv);
            bv = ok ? v[j] : bv;
            bj = ok ? j : bj;
        }
        int btok = tid + (bj << 8);

        // 64-lane butterfly reduce: max value, tie -> smaller token id
        #pragma unroll
        for (int off = 32; off > 0; off >>= 1) {
            float ov = __shfl_xor(bv, off);
            int   ot = __shfl_xor(btok, off);
            bool take = (ov > bv) || (ov == bv && ot < btok);
            bv   = take ? ov : bv;
            btok = take ? ot : btok;
        }
        if (lane == 0) { sval[wv] = bv; sidx[wv] = btok; }
        __syncthreads();
        if (tid == 0) {
            float fv = sval[0]; int ft = sidx[0];
            #pragma unroll
            for (int wq = 1; wq < 4; ++wq) {
                bool take = (sval[wq] > fv) || (sval[wq] == fv && sidx[wq] < ft);
                fv = take ? sval[wq] : fv;
                ft = take ? sidx[wq] : ft;
            }
            wtok = ft;
            out_idx[e * CAP + c] = (float)ft;
            out_mask[(size_t)ft * NEXP + e] = 1.0f;
        }
        __syncthreads();
        int ft = wtok;
        if ((ft & 255) == tid) sel |= 1u << (ft >> 8);   // static shift, no reg-array index
    }
}

// ---------------- Kernel 3: loss ----------------
// expert_load is structurally exactly CAP for every expert (top-k selects CAP
// distinct tokens). fp32: load/mean = 1.0f; 1.0f + 1e-8f == 1.0f; logf(1.0f) == 0.
__global__ void loss_kernel(float* __restrict__ out_loss) {
    float ld = (float)CAP;
    float mean = (float)CAP;
    out_loss[0] = ld * logf(ld / mean + 1e-8f);   // == 0.0f in fp32
}

extern "C" void kernel_launch(void* const* d_in, const int* in_sizes, int n_in,
                              void* d_out, int out_size, void* d_ws, size_t ws_size,
                              hipStream_t stream) {
    const float* x = (const float*)d_in[0];
    const float* w = (const float*)d_in[1];

    float* out      = (float*)d_out;
    float* out_idx  = out;                            // [64][160]   fp32
    float* out_mask = out + NEXP * CAP;               // [8192][64]  fp32
    float* out_loss = out + NEXP * CAP + NTOK * NEXP; // [1]         fp32

    int n4 = NTOK * NEXP / 4;  // 131072 float4s in mask region
    init_out<<<(n4 + 255) / 256, 256, 0, stream>>>((float4*)out_mask, n4);

    gemm_logits<<<NTOK / TB, 256, 0, stream>>>(x, w);

    topk_kernel<<<NEXP, 256, 0, stream>>>(out_idx, out_mask);

    loss_kernel<<<1, 1, 0, stream>>>(out_loss);
}

// Round 7
// 242.351 us; speedup vs baseline: 1.8174x; 1.8174x over previous
//
#include <hip/hip_runtime.h>

#define NTOK 8192
#define HDIM 4096
#define NEXP 64
#define CAP  160   // int(8192 * 1.25 / 64)
#define TB   16    // tokens per gemm block
#define KC   128   // K chunk

// logits transposed [expert][token], fp32 — 2 MB device global
__device__ float g_lt[NEXP * NTOK];

__device__ __forceinline__ unsigned int flip_key(float f) {
    unsigned int u = __float_as_uint(f);
    return u ^ (unsigned int)(((int)u >> 31) | 0x80000000);
}

// ---------------- Kernel 1: logits = x @ gate_w (fp64 acc), fused mask-zero ----
// grid 512, block 512 (8 waves). Wave wv: lanes = experts, tokens wv*2, wv*2+1.
__global__ __launch_bounds__(512) void gemm_logits(const float* __restrict__ x,
                                                   const float* __restrict__ w,
                                                   float* __restrict__ out_mask,
                                                   float* __restrict__ out_loss) {
    __shared__ float xs[TB][KC];      // 8 KB
    __shared__ float wsh[KC][NEXP];   // 32 KB
    const int tid  = threadIdx.x;
    const int lane = tid & 63;
    const int wv   = tid >> 6;        // 0..7
    const int t0   = blockIdx.x * TB;
    const int row0 = wv * 2;

    // fused: zero this block's 16 rows of the dispatch mask (256 float4)
    if (tid < 256)
        ((float4*)out_mask)[blockIdx.x * 256 + tid] = float4{0.f, 0.f, 0.f, 0.f};
    // loss is structurally 0: load==CAP for all experts; logf(1.0f+1e-8f)==0 in fp32
    if (blockIdx.x == 0 && tid == 0) out_loss[0] = 0.0f;

    double acc0 = 0.0, acc1 = 0.0;

    const float4* x4 = (const float4*)x;
    const float4* w4 = (const float4*)w;
    float4* xs4 = (float4*)&xs[0][0];
    float4* ws4 = (float4*)&wsh[0][0];

    for (int kc = 0; kc < HDIM; kc += KC) {
        __syncthreads();
        #pragma unroll
        for (int j = 0; j < 4; ++j)   // w chunk: 2048 float4
            ws4[tid + j * 512] = w4[(kc * NEXP) / 4 + tid + j * 512];
        {                              // x chunk: 512 float4, one per thread
            int t = tid >> 5, c = tid & 31;
            xs4[t * 32 + c] = x4[(size_t)(t0 + t) * (HDIM / 4) + kc / 4 + c];
        }
        __syncthreads();

        #pragma unroll 8
        for (int k4 = 0; k4 < KC / 4; ++k4) {
            float4 xv0 = *(const float4*)&xs[row0][k4 * 4];      // broadcast
            float4 xv1 = *(const float4*)&xs[row0 + 1][k4 * 4];  // broadcast
            float w0 = wsh[k4 * 4 + 0][lane];
            float w1 = wsh[k4 * 4 + 1][lane];
            float w2 = wsh[k4 * 4 + 2][lane];
            float w3 = wsh[k4 * 4 + 3][lane];
            acc0 = fma((double)xv0.x, (double)w0, acc0);
            acc0 = fma((double)xv0.y, (double)w1, acc0);
            acc0 = fma((double)xv0.z, (double)w2, acc0);
            acc0 = fma((double)xv0.w, (double)w3, acc0);
            acc1 = fma((double)xv1.x, (double)w0, acc1);
            acc1 = fma((double)xv1.y, (double)w1, acc1);
            acc1 = fma((double)xv1.z, (double)w2, acc1);
            acc1 = fma((double)xv1.w, (double)w3, acc1);
        }
    }

    g_lt[(size_t)lane * NTOK + t0 + row0]     = (float)acc0;
    g_lt[(size_t)lane * NTOK + t0 + row0 + 1] = (float)acc1;
}

// ---------------- Kernel 2: per-expert top-CAP via key bisection + bitonic sort --
// 64 blocks (1/expert), 256 threads. Thread t owns tokens [t*32, t*32+32).
__global__ __launch_bounds__(256) void topk_kernel(float* __restrict__ out_idx,
                                                   float* __restrict__ out_mask) {
    const int e    = blockIdx.x;
    const int tid  = threadIdx.x;
    const int lane = tid & 63;
    const int wv   = tid >> 6;

    unsigned int k32[32];
    const float4* row4 = (const float4*)(g_lt + (size_t)e * NTOK);
    #pragma unroll
    for (int q = 0; q < 8; ++q) {
        float4 f = row4[tid * 8 + q];
        k32[q * 4 + 0] = flip_key(f.x);
        k32[q * 4 + 1] = flip_key(f.y);
        k32[q * 4 + 2] = flip_key(f.z);
        k32[q * 4 + 3] = flip_key(f.w);
    }

    __shared__ int scnt[4];

    // MSB-first greedy: p = max T with count(key >= T) >= CAP  (== CAP-th largest key)
    unsigned int p = 0;
    for (int b = 31; b >= 0; --b) {
        unsigned int cand = p | (1u << b);
        int cl = 0;
        #pragma unroll
        for (int j = 0; j < 32; ++j) cl += (k32[j] >= cand);
        #pragma unroll
        for (int off = 32; off > 0; off >>= 1) cl += __shfl_xor(cl, off);
        if (lane == 0) scnt[wv] = cl;
        __syncthreads();
        int c = scnt[0] + scnt[1] + scnt[2] + scnt[3];
        if (c >= CAP) p = cand;
        __syncthreads();
    }

    // strict-greater count g (g <= CAP-1 by maximality of p)
    int gl = 0;
    #pragma unroll
    for (int j = 0; j < 32; ++j) gl += (k32[j] > p);
    #pragma unroll
    for (int off = 32; off > 0; off >>= 1) gl += __shfl_xor(gl, off);
    if (lane == 0) scnt[wv] = gl;
    __syncthreads();
    int g = scnt[0] + scnt[1] + scnt[2] + scnt[3];

    // equals: pick the (CAP-g) smallest token ids among key==p (stable top_k tie rule)
    __shared__ int eqn, eqm;
    __shared__ int eqtok[192];
    if (tid == 0) eqn = 0;
    __syncthreads();
    #pragma unroll
    for (int j = 0; j < 32; ++j)
        if (k32[j] == p) {
            int pos = atomicAdd(&eqn, 1);
            if (pos < 192) eqtok[pos] = tid * 32 + j;
        }
    __syncthreads();
    if (tid == 0) {
        int n = eqn < 192 ? eqn : 192;
        for (int a = 0; a < n; ++a)           // tiny selection sort ascending
            for (int b2 = a + 1; b2 < n; ++b2)
                if (eqtok[b2] < eqtok[a]) { int t2 = eqtok[a]; eqtok[a] = eqtok[b2]; eqtok[b2] = t2; }
        eqm = CAP - g;
    }
    __syncthreads();
    const int m = eqm;

    // append selected (key, token) -> LDS list (order arbitrary), pad to 256
    __shared__ unsigned long long sk[256];
    __shared__ int snum;
    if (tid == 0) snum = 0;
    sk[tid] = 0ULL;
    __syncthreads();
    #pragma unroll
    for (int j = 0; j < 32; ++j) {
        int tok = tid * 32 + j;
        bool sel = (k32[j] > p);
        if (!sel && k32[j] == p)
            for (int a = 0; a < m; ++a) sel = sel || (eqtok[a] == tok);
        if (sel) {
            int pos = atomicAdd(&snum, 1);
            sk[pos] = ((unsigned long long)k32[j] << 13) | (unsigned int)(8191 - tok);
        }
    }
    __syncthreads();

    // bitonic sort 256 descending (key desc; tie -> larger (8191-tok) = smaller tok first)
    for (int size = 2; size <= 256; size <<= 1) {
        for (int stride = size >> 1; stride > 0; stride >>= 1) {
            int i = tid, jj = i ^ stride;
            if (jj > i) {
                unsigned long long a = sk[i], b2 = sk[jj];
                bool desc = ((i & size) == 0);
                if (desc ? (a < b2) : (a > b2)) { sk[i] = b2; sk[jj] = a; }
            }
            __syncthreads();
        }
    }

    if (tid < CAP) {
        int tok = 8191 - (int)(sk[tid] & 0x1FFFULL);
        out_idx[e * CAP + tid] = (float)tok;
        out_mask[(size_t)tok * NEXP + e] = 1.0f;
    }
}

extern "C" void kernel_launch(void* const* d_in, const int* in_sizes, int n_in,
                              void* d_out, int out_size, void* d_ws, size_t ws_size,
                              hipStream_t stream) {
    const float* x = (const float*)d_in[0];
    const float* w = (const float*)d_in[1];

    float* out      = (float*)d_out;
    float* out_idx  = out;                            // [64][160]
    float* out_mask = out + NEXP * CAP;               // [8192][64]
    float* out_loss = out + NEXP * CAP + NTOK * NEXP; // [1]

    gemm_logits<<<NTOK / TB, 512, 0, stream>>>(x, w, out_mask, out_loss);
    topk_kernel<<<NEXP, 256, 0, stream>>>(out_idx, out_mask);
}

// Round 8
// 228.697 us; speedup vs baseline: 1.9259x; 1.0597x over previous
//
#include <hip/hip_runtime.h>

#define NTOK 8192
#define HDIM 4096
#define NEXP 64
#define CAP  160      // int(8192 * 1.25 / 64)
#define KSPLIT 2
#define KHALF (HDIM / KSPLIT)   // 2048
#define KC   64                 // k per LDS chunk
#define NCH  (KHALF / KC)       // 32 chunks

// logits transposed [expert][token], fp32 — 2 MB device global
__device__ float g_lt[NEXP * NTOK];

__device__ __forceinline__ unsigned int flip_key(float f) {
    unsigned int u = __float_as_uint(f);
    return u ^ (unsigned int)(((int)u >> 31) | 0x80000000);
}

// ---------------- Kernel 0: w -> wd (fp64), 1 MB -> 2 MB ----------------
__global__ __launch_bounds__(256) void conv_w(const float* __restrict__ w,
                                              double* __restrict__ wd) {
    int i = blockIdx.x * 256 + threadIdx.x;   // grid 1024 -> 262144
    wd[i] = (double)w[i];
}

// ---------------- Kernel 1: GEMM, lane=token, w via scalar loads ----------------
// grid 256 = 128 token-groups x KSPLIT. block 512 = 8 waves; wave wv -> experts
// [wv*8, wv*8+8), lanes = tokens tg0..tg0+63. x staged fp32 in LDS (XOR-swizzled),
// wd read at uniform addresses -> s_load_dwordx16 (8 doubles = one j-unroll).
__global__ __launch_bounds__(512) void gemm_c(const float* __restrict__ x,
                                              const double* __restrict__ wd,
                                              double* __restrict__ p) {
    __shared__ float4 xs4[2][64 * 16];   // 2 x 16 KB, [tok][k4-slot ^ (tok&7)]
    const int tid = threadIdx.x;
    const int l   = tid & 63;
    const int wv  = __builtin_amdgcn_readfirstlane(tid >> 6);  // 0..7, uniform
    const int e0  = wv * 8;
    const int tokgrp = blockIdx.x >> 1;
    const int ks     = blockIdx.x & 1;
    const int tg0    = tokgrp * 64;
    const int kbase  = ks * KHALF;

    const float4* x4 = (const float4*)x;

    double acc[8] = {0, 0, 0, 0, 0, 0, 0, 0};

    // staging assignment: 1024 float4 per chunk, 512 threads -> 2 each
    const int t0s = tid >> 4,          c0s = tid & 15;
    const int t1s = (tid + 512) >> 4,  c1s = tid & 15;   // (tid+512)&15 == tid&15
    const int d0  = t0s * 16 + (c0s ^ (t0s & 7));
    const int d1  = t1s * 16 + (c1s ^ (t1s & 7));
    const size_t rs = HDIM / 4;

    // prologue: stage chunk 0 into buffer 0
    xs4[0][d0] = x4[(size_t)(tg0 + t0s) * rs + (kbase >> 2) + c0s];
    xs4[0][d1] = x4[(size_t)(tg0 + t1s) * rs + (kbase >> 2) + c1s];

    for (int ch = 0; ch < NCH; ++ch) {
        __syncthreads();
        const int cur = ch & 1;
        const int k0  = kbase + ch * KC;

        // T14: issue next chunk's global loads BEFORE compute
        float4 r0, r1;
        const bool more = (ch + 1 < NCH);
        if (more) {
            int kn = k0 + KC;
            r0 = x4[(size_t)(tg0 + t0s) * rs + (kn >> 2) + c0s];
            r1 = x4[(size_t)(tg0 + t1s) * rs + (kn >> 2) + c1s];
        }

        #pragma unroll 4
        for (int c4 = 0; c4 < 16; ++c4) {
            float4 f = xs4[cur][l * 16 + (c4 ^ (l & 7))];   // conflict-free b128
            double dx0 = (double)f.x, dx1 = (double)f.y;
            double dx2 = (double)f.z, dx3 = (double)f.w;
            const double* wrow = wd + (size_t)(k0 + c4 * 4) * NEXP + e0;  // uniform
            #pragma unroll
            for (int j = 0; j < 8; ++j) {
                acc[j] = fma(dx0, wrow[j],            acc[j]);
                acc[j] = fma(dx1, wrow[NEXP + j],     acc[j]);
                acc[j] = fma(dx2, wrow[2 * NEXP + j], acc[j]);
                acc[j] = fma(dx3, wrow[3 * NEXP + j], acc[j]);
            }
        }

        // write-late into the other buffer (no race: readers use buf[cur])
        if (more) {
            xs4[cur ^ 1][d0] = r0;
            xs4[cur ^ 1][d1] = r1;
        }
    }

    // partials p[ks][e][tok], coalesced b64 stores
    #pragma unroll
    for (int j = 0; j < 8; ++j)
        p[((size_t)ks * NEXP + e0 + j) * NTOK + tg0 + l] = acc[j];
}

// ---------------- Kernel 2: reduce K-split partials + zero mask + loss ----------
__global__ __launch_bounds__(256) void reduce_k(const double* __restrict__ p,
                                                float* __restrict__ out_mask,
                                                float* __restrict__ out_loss) {
    int gid = blockIdx.x * 256 + threadIdx.x;   // grid 2048 -> 524288
    g_lt[gid] = (float)(p[gid] + p[(size_t)NEXP * NTOK + gid]);
    if (gid < NTOK * NEXP / 4)
        ((float4*)out_mask)[gid] = float4{0.f, 0.f, 0.f, 0.f};
    // loss structurally 0: every expert load == CAP; logf(1.0f + 1e-8f) == 0 in fp32
    if (gid == 0) out_loss[0] = 0.0f;
}

// ---------------- Kernel 3: per-expert top-CAP (bisection + bitonic) — proven ----
__global__ __launch_bounds__(256) void topk_kernel(float* __restrict__ out_idx,
                                                   float* __restrict__ out_mask) {
    const int e    = blockIdx.x;
    const int tid  = threadIdx.x;
    const int lane = tid & 63;
    const int wv   = tid >> 6;

    unsigned int k32[32];
    const float4* row4 = (const float4*)(g_lt + (size_t)e * NTOK);
    #pragma unroll
    for (int q = 0; q < 8; ++q) {
        float4 f = row4[tid * 8 + q];
        k32[q * 4 + 0] = flip_key(f.x);
        k32[q * 4 + 1] = flip_key(f.y);
        k32[q * 4 + 2] = flip_key(f.z);
        k32[q * 4 + 3] = flip_key(f.w);
    }

    __shared__ int scnt[4];

    unsigned int pth = 0;
    for (int b = 31; b >= 0; --b) {
        unsigned int cand = pth | (1u << b);
        int cl = 0;
        #pragma unroll
        for (int j = 0; j < 32; ++j) cl += (k32[j] >= cand);
        #pragma unroll
        for (int off = 32; off > 0; off >>= 1) cl += __shfl_xor(cl, off);
        if (lane == 0) scnt[wv] = cl;
        __syncthreads();
        int c = scnt[0] + scnt[1] + scnt[2] + scnt[3];
        if (c >= CAP) pth = cand;
        __syncthreads();
    }

    int gl = 0;
    #pragma unroll
    for (int j = 0; j < 32; ++j) gl += (k32[j] > pth);
    #pragma unroll
    for (int off = 32; off > 0; off >>= 1) gl += __shfl_xor(gl, off);
    if (lane == 0) scnt[wv] = gl;
    __syncthreads();
    int g = scnt[0] + scnt[1] + scnt[2] + scnt[3];

    __shared__ int eqn, eqm;
    __shared__ int eqtok[192];
    if (tid == 0) eqn = 0;
    __syncthreads();
    #pragma unroll
    for (int j = 0; j < 32; ++j)
        if (k32[j] == pth) {
            int pos = atomicAdd(&eqn, 1);
            if (pos < 192) eqtok[pos] = tid * 32 + j;
        }
    __syncthreads();
    if (tid == 0) {
        int n = eqn < 192 ? eqn : 192;
        for (int a = 0; a < n; ++a)
            for (int b2 = a + 1; b2 < n; ++b2)
                if (eqtok[b2] < eqtok[a]) { int t2 = eqtok[a]; eqtok[a] = eqtok[b2]; eqtok[b2] = t2; }
        eqm = CAP - g;
    }
    __syncthreads();
    const int m = eqm;

    __shared__ unsigned long long sk[256];
    __shared__ int snum;
    if (tid == 0) snum = 0;
    sk[tid] = 0ULL;
    __syncthreads();
    #pragma unroll
    for (int j = 0; j < 32; ++j) {
        int tok = tid * 32 + j;
        bool sel = (k32[j] > pth);
        if (!sel && k32[j] == pth)
            for (int a = 0; a < m; ++a) sel = sel || (eqtok[a] == tok);
        if (sel) {
            int pos = atomicAdd(&snum, 1);
            sk[pos] = ((unsigned long long)k32[j] << 13) | (unsigned int)(8191 - tok);
        }
    }
    __syncthreads();

    for (int size = 2; size <= 256; size <<= 1) {
        for (int stride = size >> 1; stride > 0; stride >>= 1) {
            int i = tid, jj = i ^ stride;
            if (jj > i) {
                unsigned long long a = sk[i], b2 = sk[jj];
                bool desc = ((i & size) == 0);
                if (desc ? (a < b2) : (a > b2)) { sk[i] = b2; sk[jj] = a; }
            }
            __syncthreads();
        }
    }

    if (tid < CAP) {
        int tok = 8191 - (int)(sk[tid] & 0x1FFFULL);
        out_idx[e * CAP + tid] = (float)tok;
        out_mask[(size_t)tok * NEXP + e] = 1.0f;
    }
}

extern "C" void kernel_launch(void* const* d_in, const int* in_sizes, int n_in,
                              void* d_out, int out_size, void* d_ws, size_t ws_size,
                              hipStream_t stream) {
    const float* x = (const float*)d_in[0];
    const float* w = (const float*)d_in[1];

    float* out      = (float*)d_out;
    float* out_idx  = out;                            // [64][160]
    float* out_mask = out + NEXP * CAP;               // [8192][64]
    float* out_loss = out + NEXP * CAP + NTOK * NEXP; // [1]

    double* wd = (double*)d_ws;                 // 2 MB
    double* p  = wd + (size_t)HDIM * NEXP;      // 8 MB partials [2][64][8192]

    conv_w<<<HDIM * NEXP / 256, 256, 0, stream>>>(w, wd);
    gemm_c<<<256, 512, 0, stream>>>(x, wd, p);
    reduce_k<<<NTOK * NEXP / 256, 256, 0, stream>>>(p, out_mask, out_loss);
    topk_kernel<<<NEXP, 256, 0, stream>>>(out_idx, out_mask);
}

// Round 9
// 141.637 us; speedup vs baseline: 3.1097x; 1.6147x over previous
//
#include <hip/hip_runtime.h>

#define NTOK 8192
#define HDIM 4096
#define NEXP 64
#define CAP  160      // int(8192 * 1.25 / 64)
#define KSPLIT 4
#define KPART (HDIM / KSPLIT)   // 1024
#define KC   64                 // k per LDS chunk
#define NCH  (KPART / KC)       // 16 chunks

// logits transposed [expert][token], fp32 — 2 MB device global
__device__ float g_lt[NEXP * NTOK];

__device__ __forceinline__ unsigned int flip_key(float f) {
    unsigned int u = __float_as_uint(f);
    return u ^ (unsigned int)(((int)u >> 31) | 0x80000000);
}

// ---------------- Kernel 0: w -> wd2 (fp64, repacked [k4][e][ksub]) ----------------
__global__ __launch_bounds__(256) void conv_w(const float* __restrict__ w,
                                              double* __restrict__ wd2) {
    int i = blockIdx.x * 256 + threadIdx.x;   // i = k*64 + e
    int k = i >> 6, e = i & 63;
    wd2[((size_t)(k >> 2) * NEXP + e) * 4 + (k & 3)] = (double)w[i];
}

// ---------------- Kernel 1: GEMM, lane=token, w via contiguous scalar loads ------
// grid 512 = 128 token-groups x KSPLIT. block 512 = 8 waves; wave wv -> experts
// [wv*8, wv*8+8), lanes = tokens tg0..tg0+63. x staged fp32 in LDS (XOR-swizzled).
__global__ __launch_bounds__(512) void gemm_c(const float* __restrict__ x,
                                              const double* __restrict__ wd2,
                                              double* __restrict__ p) {
    __shared__ float4 xs4[2][64 * 16];   // 2 x 16 KB
    const int tid = threadIdx.x;
    const int l   = tid & 63;
    const int wv  = __builtin_amdgcn_readfirstlane(tid >> 6);  // 0..7, uniform
    const int e0  = wv * 8;
    const int tokgrp = blockIdx.x >> 2;
    const int ks     = blockIdx.x & 3;
    const int tg0    = tokgrp * 64;
    const int kbase  = ks * KPART;

    const float4* x4 = (const float4*)x;

    double acc[8] = {0, 0, 0, 0, 0, 0, 0, 0};

    // staging: 1024 float4 per chunk, 512 threads -> 2 each
    const int t0s = tid >> 4,          c0s = tid & 15;
    const int t1s = (tid + 512) >> 4,  c1s = tid & 15;
    const int d0  = t0s * 16 + (c0s ^ (t0s & 7));
    const int d1  = t1s * 16 + (c1s ^ (t1s & 7));
    const size_t rs = HDIM / 4;

    xs4[0][d0] = x4[(size_t)(tg0 + t0s) * rs + (kbase >> 2) + c0s];
    xs4[0][d1] = x4[(size_t)(tg0 + t1s) * rs + (kbase >> 2) + c1s];

    for (int ch = 0; ch < NCH; ++ch) {
        __syncthreads();
        const int cur = ch & 1;
        const int k0  = kbase + ch * KC;

        // T14: issue next chunk's global loads BEFORE compute
        float4 r0, r1;
        const bool more = (ch + 1 < NCH);
        if (more) {
            int kn = k0 + KC;
            r0 = x4[(size_t)(tg0 + t0s) * rs + (kn >> 2) + c0s];
            r1 = x4[(size_t)(tg0 + t1s) * rs + (kn >> 2) + c1s];
        }

        #pragma unroll 4
        for (int c4 = 0; c4 < 16; ++c4) {
            float4 f = xs4[cur][l * 16 + (c4 ^ (l & 7))];   // b128, bounded conflict
            double dx0 = (double)f.x, dx1 = (double)f.y;
            double dx2 = (double)f.z, dx3 = (double)f.w;
            // 32 contiguous doubles (256 B): experts e0..e0+7 x ksub 0..3
            const double* wb = wd2 + ((size_t)((k0 >> 2) + c4) * NEXP + e0) * 4;
            #pragma unroll
            for (int j = 0; j < 8; ++j) {
                acc[j] = fma(dx0, wb[j * 4 + 0], acc[j]);
                acc[j] = fma(dx1, wb[j * 4 + 1], acc[j]);
                acc[j] = fma(dx2, wb[j * 4 + 2], acc[j]);
                acc[j] = fma(dx3, wb[j * 4 + 3], acc[j]);
            }
        }

        if (more) {
            xs4[cur ^ 1][d0] = r0;
            xs4[cur ^ 1][d1] = r1;
        }
    }

    #pragma unroll
    for (int j = 0; j < 8; ++j)
        p[((size_t)ks * NEXP + e0 + j) * NTOK + tg0 + l] = acc[j];
}

// ---------------- Kernel 2: reduce K-split partials + zero mask + loss ----------
__global__ __launch_bounds__(256) void reduce_k(const double* __restrict__ p,
                                                float* __restrict__ out_mask,
                                                float* __restrict__ out_loss) {
    int gid = blockIdx.x * 256 + threadIdx.x;   // grid 2048 -> 524288
    const size_t S = (size_t)NEXP * NTOK;
    g_lt[gid] = (float)(((p[gid] + p[S + gid]) + p[2 * S + gid]) + p[3 * S + gid]);
    if (gid < NTOK * NEXP / 4)
        ((float4*)out_mask)[gid] = float4{0.f, 0.f, 0.f, 0.f};
    // loss structurally 0: every expert load == CAP; logf(1.0f + 1e-8f) == 0 in fp32
    if (gid == 0) out_loss[0] = 0.0f;
}

// ---------------- Kernel 3: per-expert top-CAP (bisection + bitonic) — proven ----
__global__ __launch_bounds__(256) void topk_kernel(float* __restrict__ out_idx,
                                                   float* __restrict__ out_mask) {
    const int e    = blockIdx.x;
    const int tid  = threadIdx.x;
    const int lane = tid & 63;
    const int wv   = tid >> 6;

    unsigned int k32[32];
    const float4* row4 = (const float4*)(g_lt + (size_t)e * NTOK);
    #pragma unroll
    for (int q = 0; q < 8; ++q) {
        float4 f = row4[tid * 8 + q];
        k32[q * 4 + 0] = flip_key(f.x);
        k32[q * 4 + 1] = flip_key(f.y);
        k32[q * 4 + 2] = flip_key(f.z);
        k32[q * 4 + 3] = flip_key(f.w);
    }

    __shared__ int scnt[4];

    unsigned int pth = 0;
    for (int b = 31; b >= 0; --b) {
        unsigned int cand = pth | (1u << b);
        int cl = 0;
        #pragma unroll
        for (int j = 0; j < 32; ++j) cl += (k32[j] >= cand);
        #pragma unroll
        for (int off = 32; off > 0; off >>= 1) cl += __shfl_xor(cl, off);
        if (lane == 0) scnt[wv] = cl;
        __syncthreads();
        int c = scnt[0] + scnt[1] + scnt[2] + scnt[3];
        if (c >= CAP) pth = cand;
        __syncthreads();
    }

    int gl = 0;
    #pragma unroll
    for (int j = 0; j < 32; ++j) gl += (k32[j] > pth);
    #pragma unroll
    for (int off = 32; off > 0; off >>= 1) gl += __shfl_xor(gl, off);
    if (lane == 0) scnt[wv] = gl;
    __syncthreads();
    int g = scnt[0] + scnt[1] + scnt[2] + scnt[3];

    __shared__ int eqn, eqm;
    __shared__ int eqtok[192];
    if (tid == 0) eqn = 0;
    __syncthreads();
    #pragma unroll
    for (int j = 0; j < 32; ++j)
        if (k32[j] == pth) {
            int pos = atomicAdd(&eqn, 1);
            if (pos < 192) eqtok[pos] = tid * 32 + j;
        }
    __syncthreads();
    if (tid == 0) {
        int n = eqn < 192 ? eqn : 192;
        for (int a = 0; a < n; ++a)
            for (int b2 = a + 1; b2 < n; ++b2)
                if (eqtok[b2] < eqtok[a]) { int t2 = eqtok[a]; eqtok[a] = eqtok[b2]; eqtok[b2] = t2; }
        eqm = CAP - g;
    }
    __syncthreads();
    const int m = eqm;

    __shared__ unsigned long long sk[256];
    __shared__ int snum;
    if (tid == 0) snum = 0;
    sk[tid] = 0ULL;
    __syncthreads();
    #pragma unroll
    for (int j = 0; j < 32; ++j) {
        int tok = tid * 32 + j;
        bool sel = (k32[j] > pth);
        if (!sel && k32[j] == pth)
            for (int a = 0; a < m; ++a) sel = sel || (eqtok[a] == tok);
        if (sel) {
            int pos = atomicAdd(&snum, 1);
            sk[pos] = ((unsigned long long)k32[j] << 13) | (unsigned int)(8191 - tok);
        }
    }
    __syncthreads();

    for (int size = 2; size <= 256; size <<= 1) {
        for (int stride = size >> 1; stride > 0; stride >>= 1) {
            int i = tid, jj = i ^ stride;
            if (jj > i) {
                unsigned long long a = sk[i], b2 = sk[jj];
                bool desc = ((i & size) == 0);
                if (desc ? (a < b2) : (a > b2)) { sk[i] = b2; sk[jj] = a; }
            }
            __syncthreads();
        }
    }

    if (tid < CAP) {
        int tok = 8191 - (int)(sk[tid] & 0x1FFFULL);
        out_idx[e * CAP + tid] = (float)tok;
        out_mask[(size_t)tok * NEXP + e] = 1.0f;
    }
}

extern "C" void kernel_launch(void* const* d_in, const int* in_sizes, int n_in,
                              void* d_out, int out_size, void* d_ws, size_t ws_size,
                              hipStream_t stream) {
    const float* x = (const float*)d_in[0];
    const float* w = (const float*)d_in[1];

    float* out      = (float*)d_out;
    float* out_idx  = out;                            // [64][160]
    float* out_mask = out + NEXP * CAP;               // [8192][64]
    float* out_loss = out + NEXP * CAP + NTOK * NEXP; // [1]

    double* wd2 = (double*)d_ws;                 // 2 MB repacked fp64 w
    double* p   = wd2 + (size_t)HDIM * NEXP;     // 16 MB partials [4][64][8192]

    conv_w<<<HDIM * NEXP / 256, 256, 0, stream>>>(w, wd2);
    gemm_c<<<512, 512, 0, stream>>>(x, wd2, p);
    reduce_k<<<NTOK * NEXP / 256, 256, 0, stream>>>(p, out_mask, out_loss);
    topk_kernel<<<NEXP, 256, 0, stream>>>(out_idx, out_mask);
}